// Round 4
// baseline (547.814 us; speedup 1.0000x reference)
//
#include <hip/hip_runtime.h>
#include <hip/hip_bf16.h>
#include <stdint.h>

// SymbolicDecoder fused MLP evaluation, MI355X gfx950.  Round 4.
// Changes vs round 3:
//  - Balanced XCD work assignment: each XCD gets {96 T0, 32 T1, 32 T2,
//    448 T3, 96 T4} blocks (uniform 1152 work-units/XCD; round 3's chunked
//    swizzle gave XCD0 704 units and XCDs 2-6 1408 -> 22% makespan loss).
//  - Minimum-2-phase pipeline (T3 recipe): double-buffered LDS (2 distinct
//    static arrays per operand -> no alias-analysis serialization), STAGE of
//    tile k+1 issued before COMPUTE of tile k, ONE __syncthreads per k-step
//    (its vmcnt(0) drain is the counted wait for the prefetched tile).
// d_ws layout (ushorts): [0, 6291456) weights bf16 fragment-ready;
// [6291456, 35651584) feat bf16 natural [4096][7][1024].  Total 71.3 MB.

typedef __attribute__((ext_vector_type(4))) float f32x4;
typedef __attribute__((ext_vector_type(8))) short short8;
typedef __attribute__((ext_vector_type(8))) __bf16 bf16x8;

__device__ inline unsigned short f2bf(float f) {
  union { float f; uint32_t u; } x; x.f = f;
  uint32_t u = x.u;
  return (unsigned short)((u + 0x7fffu + ((u >> 16) & 1u)) >> 16);
}

// ---------------- out init: out[b][p][c] = b2(part(p))[c] ----------------
__global__ void init_out(float* __restrict__ out,
                         const float* __restrict__ sb2,
                         const float* __restrict__ db2) {
  int i = blockIdx.x * 256 + threadIdx.x;
  if (i >= 180224) return;
  int c = i & 1;
  int p = (i >> 1) % 22;
  float v;
  if (p < 3)       v = sb2[0 + c];
  else if (p == 3) v = sb2[2 + c];
  else if (p == 4) v = sb2[4 + c];
  else if (p < 19) v = db2[c];
  else             v = sb2[6 + c];
  out[i] = v;
}

// ---------------- weight prep: f32 -> bf16, fragment-ready layout --------
// Per (kstep, coltile) 32KB tile, 16B chunk c2 = kk*1024+nblk*64+kgrp*16+j15
//   k = kstep*64 + kk*32 + kgrp*8 + e (e=0..7) ; j = coltile*256 + nblk*16 + j15
__global__ void prep_weights(const float* __restrict__ sw1,
                             const float* __restrict__ dw1,
                             unsigned short* __restrict__ wp) {
  int c = blockIdx.x * 256 + threadIdx.x;  // 786432 chunks total
  const float* W;
  size_t ob;
  int local;
  if (c < 524288) {
    int net = c >> 17;
    local = c & 131071;
    W = sw1 + (size_t)net * 1048576;
    ob = (size_t)net * 1048576;
  } else {
    local = c - 524288;
    W = dw1;
    ob = 4194304;
  }
  int c2 = local & 2047;
  int tile = local >> 11;
  int ct = tile & 3;
  int kstep = tile >> 2;
  int kk = c2 >> 10, nblk = (c2 >> 6) & 15, kgrp = (c2 >> 4) & 3, j15 = c2 & 15;
  int kb = kstep * 64 + kk * 32 + kgrp * 8;
  int j = ct * 256 + nblk * 16 + j15;
  short8 v;
#pragma unroll
  for (int e = 0; e < 8; e++) v[e] = (short)f2bf(W[(size_t)(kb + e) * 1024 + j]);
  *(short8*)(wp + ob + (size_t)local * 8) = v;
}

// ---------------- feat prep: f32 -> bf16, natural layout ----------------
__global__ void prep_feat(const float* __restrict__ feat,
                          unsigned short* __restrict__ fb) {
  int i = blockIdx.x * 256 + threadIdx.x;  // 3670016 chunks of 8
  const float* s = feat + (size_t)i * 8;
  f32x4 a = *(const f32x4*)s;
  f32x4 b = *(const f32x4*)(s + 4);
  short8 v;
  v[0] = (short)f2bf(a[0]); v[1] = (short)f2bf(a[1]);
  v[2] = (short)f2bf(a[2]); v[3] = (short)f2bf(a[3]);
  v[4] = (short)f2bf(b[0]); v[5] = (short)f2bf(b[1]);
  v[6] = (short)f2bf(b[2]); v[7] = (short)f2bf(b[3]);
  *(short8*)(fb + (size_t)i * 8) = v;
}

// ---------------- fused main: 64 rows x 256 cols per block --------------
__global__ __launch_bounds__(256) void fused_main(
    const float* __restrict__ sb1, const float* __restrict__ sw2,
    const float* __restrict__ db1, const float* __restrict__ dw2,
    const unsigned short* __restrict__ wp,
    const unsigned short* __restrict__ fb, float* __restrict__ out) {
  // double-buffered, distinct static arrays (alias-analysis friendly)
  __shared__ short8 Abuf0[512];    // 8 KB each
  __shared__ short8 Abuf1[512];
  __shared__ short8 Bbuf0[2048];   // 32 KB each
  __shared__ short8 Bbuf1[2048];   // total 80 KB -> 2 blocks/CU

  const int tid = threadIdx.x;
  const int lane = tid & 63;
  const int wid = tid >> 6;
  const int r15 = lane & 15;
  const int fr = (lane >> 4) * 16 + r15;   // fragment row within 64

  // Balanced XCD assignment: xcd = bid&7 (round-robin dispatch), j = stream
  // position.  Per-XCD stream: [0,96) T0 | [96,128) T1 | [128,160) T2 |
  // [160,608) T3 | [608,704) T4.  Within task, v = xcd*chunk + (j-base),
  // ct = v&3 (4 col-tiles of one row-tile adjacent), rt = v>>2.
  const int bid = blockIdx.x;
  const int x = bid & 7;
  const int j = bid >> 3;

  int task, nsteps, v;
  const unsigned short* wpt;
  const float* b1;
  const float* w2;
  if (j < 96)       { task = 0; v = x * 96 + j;         wpt = wp;           b1 = sb1;        w2 = sw2;        nsteps = 16; }
  else if (j < 128) { task = 1; v = x * 32 + (j - 96);  wpt = wp + 1048576; b1 = sb1 + 1024; w2 = sw2 + 2048; nsteps = 16; }
  else if (j < 160) { task = 2; v = x * 32 + (j - 128); wpt = wp + 2097152; b1 = sb1 + 2048; w2 = sw2 + 4096; nsteps = 16; }
  else if (j < 608) { task = 3; v = x * 448 + (j - 160); wpt = wp + 4194304; b1 = db1;       w2 = dw2;        nsteps = 32; }
  else              { task = 4; v = x * 96 + (j - 608); wpt = wp + 3145728; b1 = sb1 + 3072; w2 = sw2 + 6144; nsteps = 16; }
  const int ct = v & 3;
  const int rbase = (v >> 2) * 64;

  // A staging: thread (wid,lane) owns row rbase + wid*16 + r15,
  // k-chunk (lane>>4)*8.
  const unsigned short *p0, *p1;
  {
    int arow = rbase + wid * 16 + r15;
    int ab, as1, as2;
    if (task == 0 || task == 4) {
      ab = arow / 3; int s = arow - ab * 3; as1 = s; as2 = s;
    } else if (task == 3) {
      ab = arow / 14; int pp = arow - ab * 14;
      if (pp < 12) { as1 = pp >> 2; as2 = 3 + (pp & 3); }
      else         { as1 = 4;       as2 = (pp == 12) ? 5 : 6; }
    } else {
      ab = arow; as1 = 6; as2 = 6;
    }
    int kl = (lane >> 4) * 8;
    p0 = fb + ((size_t)ab * 7 + as1) * 1024 + kl;
    p1 = fb + ((size_t)ab * 7 + as2) * 1024 + kl;
  }

  f32x4 acc[4][4] = {};

#define STAGE(KS, AB, BB)                                                     \
  do {                                                                        \
    const int ko_ = ((KS) & 15) * 64;                                         \
    const unsigned short* a_ = ((KS) < 16) ? p0 : p1;                         \
    __builtin_amdgcn_global_load_lds(                                         \
        (const __attribute__((address_space(1))) void*)(a_ + ko_),            \
        (__attribute__((address_space(3))) void*)((char*)(AB) + wid * 1024),  \
        16, 0, 0);                                                            \
    __builtin_amdgcn_global_load_lds(                                         \
        (const __attribute__((address_space(1))) void*)(a_ + ko_ + 32),       \
        (__attribute__((address_space(3))) void*)((char*)(AB) + 4096 + wid * 1024), \
        16, 0, 0);                                                            \
    const unsigned short* ws_ = wpt + (size_t)((KS) * 4 + ct) * 16384;        \
    _Pragma("unroll")                                                         \
    for (int i_ = 0; i_ < 8; i_++) {                                          \
      __builtin_amdgcn_global_load_lds(                                       \
          (const __attribute__((address_space(1))) void*)(ws_ + i_ * 2048 + tid * 8), \
          (__attribute__((address_space(3))) void*)((char*)(BB) + i_ * 4096 + wid * 1024), \
          16, 0, 0);                                                          \
    }                                                                         \
  } while (0)

#define COMPUTE(AB, BB)                                                       \
  do {                                                                        \
    _Pragma("unroll")                                                         \
    for (int kk_ = 0; kk_ < 2; kk_++) {                                       \
      short8 afr[4], bfr[4];                                                  \
      _Pragma("unroll")                                                       \
      for (int m_ = 0; m_ < 4; m_++)                                          \
        afr[m_] = (AB)[kk_ * 256 + m_ * 64 + fr];                             \
      _Pragma("unroll")                                                       \
      for (int n_ = 0; n_ < 4; n_++)                                          \
        bfr[n_] = (BB)[kk_ * 1024 + (wid * 4 + n_) * 64 + fr];                \
      _Pragma("unroll")                                                       \
      for (int m_ = 0; m_ < 4; m_++)                                          \
        _Pragma("unroll")                                                     \
        for (int n_ = 0; n_ < 4; n_++)                                        \
          acc[m_][n_] = __builtin_amdgcn_mfma_f32_16x16x32_bf16(              \
              __builtin_bit_cast(bf16x8, afr[m_]),                            \
              __builtin_bit_cast(bf16x8, bfr[n_]), acc[m_][n_], 0, 0, 0);     \
    }                                                                         \
  } while (0)

  // prologue: stage tile 0 into buffer 0, drain, barrier
  STAGE(0, Abuf0, Bbuf0);
  __syncthreads();

  // 2-phase main loop: one barrier per k-step; STAGE(next) issued before
  // COMPUTE(cur); __syncthreads' vmcnt(0) is the wait for the prefetch.
  for (int ks = 0; ks < nsteps; ks += 2) {
    STAGE(ks + 1, Abuf1, Bbuf1);
    COMPUTE(Abuf0, Bbuf0);
    __syncthreads();
    if (ks + 2 < nsteps) STAGE(ks + 2, Abuf0, Bbuf0);
    COMPUTE(Abuf1, Bbuf1);
    __syncthreads();
  }
#undef STAGE
#undef COMPUTE

  // ---- epilogue: h = relu(acc + b1); partial out = h . w2 ; atomicAdd ----
  float b1v[4], w20v[4], w21v[4];
#pragma unroll
  for (int n = 0; n < 4; n++) {
    int jj = ct * 256 + wid * 64 + n * 16 + r15;
    b1v[n] = b1[jj];
    w20v[n] = w2[2 * jj];
    w21v[n] = w2[2 * jj + 1];
  }
#pragma unroll
  for (int m = 0; m < 4; m++) {
#pragma unroll
    for (int r = 0; r < 4; r++) {
      float s0 = 0.f, s1 = 0.f;
#pragma unroll
      for (int n = 0; n < 4; n++) {
        float h = acc[m][n][r] + b1v[n];
        h = fmaxf(h, 0.f);
        s0 = fmaf(h, w20v[n], s0);
        s1 = fmaf(h, w21v[n], s1);
      }
#pragma unroll
      for (int off = 1; off < 16; off <<= 1) {
        s0 += __shfl_xor(s0, off, 64);
        s1 += __shfl_xor(s1, off, 64);
      }
      if (r15 == 0) {
        int rg = rbase + m * 16 + (lane >> 4) * 4 + r;
        int b, p;
        if (task == 0)      { b = rg / 3;  p = rg - b * 3; }
        else if (task == 1) { b = rg;      p = 3; }
        else if (task == 2) { b = rg;      p = 4; }
        else if (task == 3) { b = rg / 14; p = 5 + (rg - b * 14); }
        else                { b = rg / 3;  p = 19 + (rg - b * 3); }
        atomicAdd(out + ((size_t)b * 44 + p * 2), s0);
        atomicAdd(out + ((size_t)b * 44 + p * 2 + 1), s1);
      }
    }
  }
}

extern "C" void kernel_launch(void* const* d_in, const int* in_sizes, int n_in,
                              void* d_out, int out_size, void* d_ws, size_t ws_size,
                              hipStream_t stream) {
  const float* feat = (const float*)d_in[0];
  const float* sw1  = (const float*)d_in[1];
  const float* sb1  = (const float*)d_in[2];
  const float* sw2  = (const float*)d_in[3];
  const float* sb2  = (const float*)d_in[4];
  const float* dw1  = (const float*)d_in[5];
  const float* db1  = (const float*)d_in[6];
  const float* dw2  = (const float*)d_in[7];
  const float* db2  = (const float*)d_in[8];
  float* out = (float*)d_out;
  unsigned short* wp = (unsigned short*)d_ws;      // 12.58 MB weights
  unsigned short* fb = wp + 6291456;               // 58.7 MB feat bf16

  init_out<<<704, 256, 0, stream>>>(out, sb2, db2);
  prep_weights<<<3072, 256, 0, stream>>>(sw1, dw1, wp);
  prep_feat<<<14336, 256, 0, stream>>>(feat, fb);
  // 5632 blocks = 8 XCD streams x 704 (96 T0 | 32 T1 | 32 T2 | 448 T3 | 96 T4)
  fused_main<<<5632, 256, 0, stream>>>(sb1, sw2, db1, dw2, wp, fb, out);
}

// Round 5
// 466.787 us; speedup vs baseline: 1.1736x; 1.1736x over previous
//
#include <hip/hip_runtime.h>
#include <hip/hip_bf16.h>
#include <stdint.h>

// SymbolicDecoder fused MLP evaluation, MI355X gfx950.  Round 5.
// Change vs round 4: T4 counted-vmcnt pipeline.  __syncthreads (which drains
// vmcnt(0), killing the prefetch) replaced by raw s_barrier + hand-counted
// s_waitcnt: steady state keeps 20 global_load_lds in flight (tiles t,t+1);
// consuming tile t waits vmcnt(10) only.  Re-stage of a buffer is fenced by
// lgkmcnt(0)+barrier after all fragment reads of that buffer.
// d_ws layout (ushorts): [0, 6291456) weights bf16 fragment-ready;
// [6291456, 35651584) feat bf16 natural [4096][7][1024].  Total 71.3 MB.

typedef __attribute__((ext_vector_type(4))) float f32x4;
typedef __attribute__((ext_vector_type(8))) short short8;
typedef __attribute__((ext_vector_type(8))) __bf16 bf16x8;

__device__ inline unsigned short f2bf(float f) {
  union { float f; uint32_t u; } x; x.f = f;
  uint32_t u = x.u;
  return (unsigned short)((u + 0x7fffu + ((u >> 16) & 1u)) >> 16);
}

// ---------------- out init: out[b][p][c] = b2(part(p))[c] ----------------
__global__ void init_out(float* __restrict__ out,
                         const float* __restrict__ sb2,
                         const float* __restrict__ db2) {
  int i = blockIdx.x * 256 + threadIdx.x;
  if (i >= 180224) return;
  int c = i & 1;
  int p = (i >> 1) % 22;
  float v;
  if (p < 3)       v = sb2[0 + c];
  else if (p == 3) v = sb2[2 + c];
  else if (p == 4) v = sb2[4 + c];
  else if (p < 19) v = db2[c];
  else             v = sb2[6 + c];
  out[i] = v;
}

// ---------------- weight prep: f32 -> bf16, fragment-ready layout --------
__global__ void prep_weights(const float* __restrict__ sw1,
                             const float* __restrict__ dw1,
                             unsigned short* __restrict__ wp) {
  int c = blockIdx.x * 256 + threadIdx.x;  // 786432 chunks total
  const float* W;
  size_t ob;
  int local;
  if (c < 524288) {
    int net = c >> 17;
    local = c & 131071;
    W = sw1 + (size_t)net * 1048576;
    ob = (size_t)net * 1048576;
  } else {
    local = c - 524288;
    W = dw1;
    ob = 4194304;
  }
  int c2 = local & 2047;
  int tile = local >> 11;
  int ct = tile & 3;
  int kstep = tile >> 2;
  int kk = c2 >> 10, nblk = (c2 >> 6) & 15, kgrp = (c2 >> 4) & 3, j15 = c2 & 15;
  int kb = kstep * 64 + kk * 32 + kgrp * 8;
  int j = ct * 256 + nblk * 16 + j15;
  short8 v;
#pragma unroll
  for (int e = 0; e < 8; e++) v[e] = (short)f2bf(W[(size_t)(kb + e) * 1024 + j]);
  *(short8*)(wp + ob + (size_t)local * 8) = v;
}

// ---------------- feat prep: f32 -> bf16, natural layout ----------------
__global__ void prep_feat(const float* __restrict__ feat,
                          unsigned short* __restrict__ fb) {
  int i = blockIdx.x * 256 + threadIdx.x;  // 3670016 chunks of 8
  const float* s = feat + (size_t)i * 8;
  f32x4 a = *(const f32x4*)s;
  f32x4 b = *(const f32x4*)(s + 4);
  short8 v;
  v[0] = (short)f2bf(a[0]); v[1] = (short)f2bf(a[1]);
  v[2] = (short)f2bf(a[2]); v[3] = (short)f2bf(a[3]);
  v[4] = (short)f2bf(b[0]); v[5] = (short)f2bf(b[1]);
  v[6] = (short)f2bf(b[2]); v[7] = (short)f2bf(b[3]);
  *(short8*)(fb + (size_t)i * 8) = v;
}

// ---------------- fused main: 64 rows x 256 cols per block --------------
__global__ __launch_bounds__(256) void fused_main(
    const float* __restrict__ sb1, const float* __restrict__ sw2,
    const float* __restrict__ db1, const float* __restrict__ dw2,
    const unsigned short* __restrict__ wp,
    const unsigned short* __restrict__ fb, float* __restrict__ out) {
  __shared__ short8 Abuf0[512];    // 8 KB each
  __shared__ short8 Abuf1[512];
  __shared__ short8 Bbuf0[2048];   // 32 KB each
  __shared__ short8 Bbuf1[2048];   // 80 KB total -> 2 blocks/CU

  const int tid = threadIdx.x;
  const int lane = tid & 63;
  const int wid = tid >> 6;
  const int r15 = lane & 15;
  const int fr = (lane >> 4) * 16 + r15;   // fragment row within 64

  // Balanced XCD assignment (round 4): xcd = bid&7, j = stream position.
  const int bid = blockIdx.x;
  const int x = bid & 7;
  const int j = bid >> 3;

  int task, nsteps, v;
  const unsigned short* wpt;
  const float* b1;
  const float* w2;
  if (j < 96)       { task = 0; v = x * 96 + j;          wpt = wp;           b1 = sb1;        w2 = sw2;        nsteps = 16; }
  else if (j < 128) { task = 1; v = x * 32 + (j - 96);   wpt = wp + 1048576; b1 = sb1 + 1024; w2 = sw2 + 2048; nsteps = 16; }
  else if (j < 160) { task = 2; v = x * 32 + (j - 128);  wpt = wp + 2097152; b1 = sb1 + 2048; w2 = sw2 + 4096; nsteps = 16; }
  else if (j < 608) { task = 3; v = x * 448 + (j - 160); wpt = wp + 4194304; b1 = db1;        w2 = dw2;        nsteps = 32; }
  else              { task = 4; v = x * 96 + (j - 608);  wpt = wp + 3145728; b1 = sb1 + 3072; w2 = sw2 + 6144; nsteps = 16; }
  const int ct = v & 3;
  const int rbase = (v >> 2) * 64;

  // A staging: thread (wid,lane) owns row rbase + wid*16 + r15,
  // k-chunk (lane>>4)*8.
  const unsigned short *p0, *p1;
  {
    int arow = rbase + wid * 16 + r15;
    int ab, as1, as2;
    if (task == 0 || task == 4) {
      ab = arow / 3; int s = arow - ab * 3; as1 = s; as2 = s;
    } else if (task == 3) {
      ab = arow / 14; int pp = arow - ab * 14;
      if (pp < 12) { as1 = pp >> 2; as2 = 3 + (pp & 3); }
      else         { as1 = 4;       as2 = (pp == 12) ? 5 : 6; }
    } else {
      ab = arow; as1 = 6; as2 = 6;
    }
    int kl = (lane >> 4) * 8;
    p0 = fb + ((size_t)ab * 7 + as1) * 1024 + kl;
    p1 = fb + ((size_t)ab * 7 + as2) * 1024 + kl;
  }

  f32x4 acc[4][4] = {};

  // STAGE(t): 10 global_load_lds (2 A + 8 B) -> vmcnt += 10
#define STAGE(KS, AB, BB)                                                     \
  do {                                                                        \
    const int ko_ = ((KS) & 15) * 64;                                         \
    const unsigned short* a_ = ((KS) < 16) ? p0 : p1;                         \
    __builtin_amdgcn_global_load_lds(                                         \
        (const __attribute__((address_space(1))) void*)(a_ + ko_),            \
        (__attribute__((address_space(3))) void*)((char*)(AB) + wid * 1024),  \
        16, 0, 0);                                                            \
    __builtin_amdgcn_global_load_lds(                                         \
        (const __attribute__((address_space(1))) void*)(a_ + ko_ + 32),       \
        (__attribute__((address_space(3))) void*)((char*)(AB) + 4096 + wid * 1024), \
        16, 0, 0);                                                            \
    const unsigned short* ws_ = wpt + (size_t)((KS) * 4 + ct) * 16384;        \
    _Pragma("unroll")                                                         \
    for (int i_ = 0; i_ < 8; i_++) {                                          \
      __builtin_amdgcn_global_load_lds(                                       \
          (const __attribute__((address_space(1))) void*)(ws_ + i_ * 2048 + tid * 8), \
          (__attribute__((address_space(3))) void*)((char*)(BB) + i_ * 4096 + wid * 1024), \
          16, 0, 0);                                                          \
    }                                                                         \
  } while (0)

  // Half-step: consume tile T from (AB,BB); re-stage T+2 into same buffers.
  // LAST selects vmcnt(0) when no younger tile is in flight.
#define HSTEP(T, AB, BB, LAST)                                                \
  do {                                                                        \
    if (LAST) asm volatile("s_waitcnt vmcnt(0)" ::: "memory");                \
    else      asm volatile("s_waitcnt vmcnt(10)" ::: "memory");               \
    __builtin_amdgcn_s_barrier();                                             \
    short8 afr[2][4], bfr[2][4];                                              \
    _Pragma("unroll")                                                         \
    for (int kk_ = 0; kk_ < 2; kk_++) {                                       \
      _Pragma("unroll")                                                       \
      for (int m_ = 0; m_ < 4; m_++)                                          \
        afr[kk_][m_] = (AB)[kk_ * 256 + m_ * 64 + fr];                        \
      _Pragma("unroll")                                                       \
      for (int n_ = 0; n_ < 4; n_++)                                          \
        bfr[kk_][n_] = (BB)[kk_ * 1024 + (wid * 4 + n_) * 64 + fr];           \
    }                                                                         \
    asm volatile("s_waitcnt lgkmcnt(0)" ::: "memory");                        \
    __builtin_amdgcn_s_barrier();                                             \
    if ((T) + 2 < nsteps) STAGE((T) + 2, AB, BB);                             \
    __builtin_amdgcn_s_setprio(1);                                            \
    _Pragma("unroll")                                                         \
    for (int kk_ = 0; kk_ < 2; kk_++)                                         \
      _Pragma("unroll")                                                       \
      for (int m_ = 0; m_ < 4; m_++)                                          \
        _Pragma("unroll")                                                     \
        for (int n_ = 0; n_ < 4; n_++)                                        \
          acc[m_][n_] = __builtin_amdgcn_mfma_f32_16x16x32_bf16(              \
              __builtin_bit_cast(bf16x8, afr[kk_][m_]),                       \
              __builtin_bit_cast(bf16x8, bfr[kk_][n_]), acc[m_][n_], 0, 0, 0);\
    __builtin_amdgcn_s_setprio(0);                                            \
  } while (0)

  // prologue: 2 tiles in flight (20 outstanding vmem ops)
  STAGE(0, Abuf0, Bbuf0);
  STAGE(1, Abuf1, Bbuf1);

  for (int ks = 0; ks < nsteps; ks += 2) {
    HSTEP(ks,     Abuf0, Bbuf0, false);
    HSTEP(ks + 1, Abuf1, Bbuf1, (ks + 2 >= nsteps));
  }
#undef STAGE
#undef HSTEP

  // ---- epilogue: h = relu(acc + b1); partial out = h . w2 ; atomicAdd ----
  float b1v[4], w20v[4], w21v[4];
#pragma unroll
  for (int n = 0; n < 4; n++) {
    int jj = ct * 256 + wid * 64 + n * 16 + r15;
    b1v[n] = b1[jj];
    w20v[n] = w2[2 * jj];
    w21v[n] = w2[2 * jj + 1];
  }
#pragma unroll
  for (int m = 0; m < 4; m++) {
#pragma unroll
    for (int r = 0; r < 4; r++) {
      float s0 = 0.f, s1 = 0.f;
#pragma unroll
      for (int n = 0; n < 4; n++) {
        float h = acc[m][n][r] + b1v[n];
        h = fmaxf(h, 0.f);
        s0 = fmaf(h, w20v[n], s0);
        s1 = fmaf(h, w21v[n], s1);
      }
#pragma unroll
      for (int off = 1; off < 16; off <<= 1) {
        s0 += __shfl_xor(s0, off, 64);
        s1 += __shfl_xor(s1, off, 64);
      }
      if (r15 == 0) {
        int rg = rbase + m * 16 + (lane >> 4) * 4 + r;
        int b, p;
        if (task == 0)      { b = rg / 3;  p = rg - b * 3; }
        else if (task == 1) { b = rg;      p = 3; }
        else if (task == 2) { b = rg;      p = 4; }
        else if (task == 3) { b = rg / 14; p = 5 + (rg - b * 14); }
        else                { b = rg / 3;  p = 19 + (rg - b * 3); }
        atomicAdd(out + ((size_t)b * 44 + p * 2), s0);
        atomicAdd(out + ((size_t)b * 44 + p * 2 + 1), s1);
      }
    }
  }
}

extern "C" void kernel_launch(void* const* d_in, const int* in_sizes, int n_in,
                              void* d_out, int out_size, void* d_ws, size_t ws_size,
                              hipStream_t stream) {
  const float* feat = (const float*)d_in[0];
  const float* sw1  = (const float*)d_in[1];
  const float* sb1  = (const float*)d_in[2];
  const float* sw2  = (const float*)d_in[3];
  const float* sb2  = (const float*)d_in[4];
  const float* dw1  = (const float*)d_in[5];
  const float* db1  = (const float*)d_in[6];
  const float* dw2  = (const float*)d_in[7];
  const float* db2  = (const float*)d_in[8];
  float* out = (float*)d_out;
  unsigned short* wp = (unsigned short*)d_ws;      // 12.58 MB weights
  unsigned short* fb = wp + 6291456;               // 58.7 MB feat bf16

  init_out<<<704, 256, 0, stream>>>(out, sb2, db2);
  prep_weights<<<3072, 256, 0, stream>>>(sw1, dw1, wp);
  prep_feat<<<14336, 256, 0, stream>>>(feat, fb);
  // 5632 blocks = 8 XCD streams x 704 (96 T0 | 32 T1 | 32 T2 | 448 T3 | 96 T4)
  fused_main<<<5632, 256, 0, stream>>>(sb1, sw2, db1, dw2, wp, fb, out);
}